// Round 1
// baseline (2092.830 us; speedup 1.0000x reference)
//
#include <hip/hip_runtime.h>
#include <hip/hip_bf16.h>

#define BATCHES 64
#define T 2048
#define DHEAD 64
#define QT 64            // q rows per block (16 per wave)
#define KTILE 64         // keys per k-tile
#define NKT (T / KTILE)  // 32

typedef __bf16 bf16x8 __attribute__((ext_vector_type(8)));
typedef float f32x4 __attribute__((ext_vector_type(4)));

__device__ __forceinline__ unsigned short f2bf(float x) {
  union { float f; unsigned u; } v; v.f = x;
  unsigned r = v.u + 0x7FFFu + ((v.u >> 16) & 1u);  // RNE
  return (unsigned short)(r >> 16);
}

// Stage a 64x64 fp32 tile (contiguous rows) into LDS as bf16, row stride 64.
__device__ __forceinline__ void stage64x64(const float* __restrict__ src,
                                           unsigned short* dst, int tid) {
  const float4* s4 = (const float4*)src;
#pragma unroll
  for (int s = 0; s < 4; ++s) {
    int i4 = tid + s * 256;          // consecutive lanes -> consecutive float4
    float4 val = s4[i4];
    unsigned lo = f2bf(val.x) | ((unsigned)f2bf(val.y) << 16);
    unsigned hi = f2bf(val.z) | ((unsigned)f2bf(val.w) << 16);
    *(uint2*)(dst + i4 * 4) = make_uint2(lo, hi);
  }
}

__global__ __launch_bounds__(256, 4)
void sdpa_kernel(const float* __restrict__ q, const float* __restrict__ kk,
                 const float* __restrict__ vv, const int* __restrict__ mask,
                 float* __restrict__ out, float* __restrict__ attn) {
  // LDS: ~35 KB total -> 4 blocks/CU
  __shared__ __attribute__((aligned(16))) unsigned short Qs[QT * DHEAD];  // [row][d]
  __shared__ __attribute__((aligned(16))) unsigned short Ks[KTILE * DHEAD]; // [key][d]
  __shared__ __attribute__((aligned(16))) unsigned short VT[DHEAD * 72];  // [d][key] padded
  __shared__ __attribute__((aligned(16))) unsigned short Ps[QT * 72];     // [row][key] padded

  const int tid  = threadIdx.x;
  const int w    = tid >> 6;
  const int lane = tid & 63;
  const int quad = lane >> 4;
  const int l15  = lane & 15;

  const int batch = blockIdx.x >> 5;        // 32 q-blocks per batch
  const int q0    = (blockIdx.x & 31) * QT;

  // ---- stage Q (once) ----
  stage64x64(q + ((size_t)batch * T + q0) * DHEAD, Qs, tid);
  __syncthreads();

  // A-frag of Q: lane holds Q[m=lane&15][k=quad*8+j] (+32 for second half of D)
  bf16x8 qf0 = *(const bf16x8*)(Qs + (w * 16 + l15) * DHEAD + quad * 8);
  bf16x8 qf1 = *(const bf16x8*)(Qs + (w * 16 + l15) * DHEAD + 32 + quad * 8);

  f32x4 oacc[4];
#pragma unroll
  for (int nt = 0; nt < 4; ++nt) oacc[nt] = (f32x4){0.f, 0.f, 0.f, 0.f};
  float lp[4] = {0.f, 0.f, 0.f, 0.f};

  // ================= PASS 1: row sums l + unnormalized PV =================
  for (int kt = 0; kt < NKT; ++kt) {
    __syncthreads();  // previous iteration's LDS consumers done
    stage64x64(kk + ((size_t)batch * T + kt * KTILE) * DHEAD, Ks, tid);
    {  // stage V transposed: VT[d][c], row stride 72 (bank-conflict pad)
      const float4* s4 = (const float4*)(vv + ((size_t)batch * T + kt * KTILE) * DHEAD);
#pragma unroll
      for (int s = 0; s < 4; ++s) {
        int i4 = tid + s * 256;
        float4 val = s4[i4];
        int c  = i4 >> 4;
        int dd = (i4 & 15) * 4;
        VT[(dd + 0) * 72 + c] = f2bf(val.x);
        VT[(dd + 1) * 72 + c] = f2bf(val.y);
        VT[(dd + 2) * 72 + c] = f2bf(val.z);
        VT[(dd + 3) * 72 + c] = f2bf(val.w);
      }
    }
    __syncthreads();

    // S = Q K^T for this wave's 16 rows x 64 keys
#pragma unroll
    for (int ct = 0; ct < 4; ++ct) {
      bf16x8 kf0 = *(const bf16x8*)(Ks + (ct * 16 + l15) * DHEAD + quad * 8);
      bf16x8 kf1 = *(const bf16x8*)(Ks + (ct * 16 + l15) * DHEAD + 32 + quad * 8);
      f32x4 acc = (f32x4){0.f, 0.f, 0.f, 0.f};
      acc = __builtin_amdgcn_mfma_f32_16x16x32_bf16(qf0, kf0, acc, 0, 0, 0);
      acc = __builtin_amdgcn_mfma_f32_16x16x32_bf16(qf1, kf1, acc, 0, 0, 0);
      // C-layout: row=(quad*4+reg), col=l15 (+ct*16)
      const int col = kt * KTILE + ct * 16 + l15;
      const size_t idx0 = ((size_t)batch * T + (q0 + w * 16 + quad * 4)) * T + col;
#pragma unroll
      for (int reg = 0; reg < 4; ++reg) {
        int m = mask[idx0 + (size_t)reg * T];
        float s = fminf(acc[reg] * 0.125f, 60.f);
        float e = m ? 0.f : __expf(s);
        lp[reg] += e;
        Ps[(w * 16 + quad * 4 + reg) * 72 + ct * 16 + l15] = f2bf(e);
      }
    }
    __syncthreads();  // cross-lane LDS dataflow: Ps writes visible before reads

    // PV: O += P(16x64) * V(64x64); P in A-layout from LDS, V^T gives B-layout
    bf16x8 pa0 = *(const bf16x8*)(Ps + (w * 16 + l15) * 72 + quad * 8);
    bf16x8 pa1 = *(const bf16x8*)(Ps + (w * 16 + l15) * 72 + 32 + quad * 8);
#pragma unroll
    for (int nt = 0; nt < 4; ++nt) {
      bf16x8 vb0 = *(const bf16x8*)(VT + (nt * 16 + l15) * 72 + quad * 8);
      bf16x8 vb1 = *(const bf16x8*)(VT + (nt * 16 + l15) * 72 + 32 + quad * 8);
      oacc[nt] = __builtin_amdgcn_mfma_f32_16x16x32_bf16(pa0, vb0, oacc[nt], 0, 0, 0);
      oacc[nt] = __builtin_amdgcn_mfma_f32_16x16x32_bf16(pa1, vb1, oacc[nt], 0, 0, 0);
    }
  }

  // reduce l across the 16 lanes holding one row's columns
  float rinv[4];
#pragma unroll
  for (int reg = 0; reg < 4; ++reg) {
    float x = lp[reg];
    x += __shfl_xor(x, 1);
    x += __shfl_xor(x, 2);
    x += __shfl_xor(x, 4);
    x += __shfl_xor(x, 8);
    rinv[reg] = x > 0.f ? 1.0f / x : 0.f;
  }

  // write out = oacc / l   (C-layout: row=quad*4+reg, col=nt*16+l15)
#pragma unroll
  for (int nt = 0; nt < 4; ++nt) {
#pragma unroll
    for (int reg = 0; reg < 4; ++reg) {
      int row = q0 + w * 16 + quad * 4 + reg;
      out[((size_t)batch * T + row) * DHEAD + nt * 16 + l15] = oacc[nt][reg] * rinv[reg];
    }
  }

  // ================= PASS 2: recompute scores, write normalized attn ======
  // reverse k order -> pass-1 mask lines most recently touched are read first
  for (int kt = NKT - 1; kt >= 0; --kt) {
    __syncthreads();
    stage64x64(kk + ((size_t)batch * T + kt * KTILE) * DHEAD, Ks, tid);
    __syncthreads();
#pragma unroll
    for (int ct = 0; ct < 4; ++ct) {
      bf16x8 kf0 = *(const bf16x8*)(Ks + (ct * 16 + l15) * DHEAD + quad * 8);
      bf16x8 kf1 = *(const bf16x8*)(Ks + (ct * 16 + l15) * DHEAD + 32 + quad * 8);
      f32x4 acc = (f32x4){0.f, 0.f, 0.f, 0.f};
      acc = __builtin_amdgcn_mfma_f32_16x16x32_bf16(qf0, kf0, acc, 0, 0, 0);
      acc = __builtin_amdgcn_mfma_f32_16x16x32_bf16(qf1, kf1, acc, 0, 0, 0);
      const int col = kt * KTILE + ct * 16 + l15;
      const size_t idx0 = ((size_t)batch * T + (q0 + w * 16 + quad * 4)) * T + col;
#pragma unroll
      for (int reg = 0; reg < 4; ++reg) {
        int m = mask[idx0 + (size_t)reg * T];
        float s = fminf(acc[reg] * 0.125f, 60.f);
        float p = m ? 0.f : __expf(s) * rinv[reg];
        attn[idx0 + (size_t)reg * T] = p;
      }
    }
  }
}

extern "C" void kernel_launch(void* const* d_in, const int* in_sizes, int n_in,
                              void* d_out, int out_size, void* d_ws, size_t ws_size,
                              hipStream_t stream) {
  const float* q    = (const float*)d_in[0];
  const float* k    = (const float*)d_in[1];
  const float* v    = (const float*)d_in[2];
  const int*   mask = (const int*)d_in[3];
  float* out  = (float*)d_out;
  float* attn = out + (size_t)BATCHES * T * DHEAD;  // (out, attn) concatenated

  dim3 grid(BATCHES * (T / QT));  // 64 * 32 = 2048 blocks
  sdpa_kernel<<<grid, 256, 0, stream>>>(q, k, v, mask, out, attn);
}